// Round 1
// baseline (766.721 us; speedup 1.0000x reference)
//
#include <hip/hip_runtime.h>
#include <hip/hip_bf16.h>
#include <math.h>

// Problem constants (from reference)
#define NNODES 100000
#define F_IN   500
#define HEADS  8
#define HID    8
#define NC     16

// ---------------------------------------------------------------------------
// CSR build
// ---------------------------------------------------------------------------
__global__ void zero_int_kernel(int* __restrict__ p, int n) {
    int i = blockIdx.x * blockDim.x + threadIdx.x;
    if (i < n) p[i] = 0;
}

__global__ void deg_kernel(const int* __restrict__ ei_dst, int* __restrict__ deg,
                           int E, int N) {
    int e = blockIdx.x * blockDim.x + threadIdx.x;
    int tot = E + N;
    if (e >= tot) return;
    int d = (e < E) ? ei_dst[e] : (e - E);   // self-loops appended
    atomicAdd(&deg[d], 1);
}

__global__ void scan1_kernel(const int* __restrict__ deg, int* __restrict__ bsum, int n) {
    __shared__ int s[256];
    int i = blockIdx.x * 256 + threadIdx.x;
    s[threadIdx.x] = (i < n) ? deg[i] : 0;
    __syncthreads();
    for (int off = 128; off > 0; off >>= 1) {
        if (threadIdx.x < off) s[threadIdx.x] += s[threadIdx.x + off];
        __syncthreads();
    }
    if (threadIdx.x == 0) bsum[blockIdx.x] = s[0];
}

__global__ void scan2_kernel(const int* __restrict__ bsum, int* __restrict__ bexcl, int nb) {
    __shared__ int s[512];
    int t = threadIdx.x;
    int orig = (t < nb) ? bsum[t] : 0;
    s[t] = orig;
    __syncthreads();
    for (int off = 1; off < 512; off <<= 1) {
        int v = (t >= off) ? s[t - off] : 0;
        __syncthreads();
        s[t] += v;
        __syncthreads();
    }
    if (t < nb) bexcl[t] = s[t] - orig;   // exclusive
}

__global__ void scan3_kernel(const int* __restrict__ deg, const int* __restrict__ bexcl,
                             int* __restrict__ rowptr, int n) {
    __shared__ int s[256];
    int t = threadIdx.x;
    int i = blockIdx.x * 256 + t;
    int v = (i < n) ? deg[i] : 0;
    s[t] = v;
    __syncthreads();
    for (int off = 1; off < 256; off <<= 1) {
        int u = (t >= off) ? s[t - off] : 0;
        __syncthreads();
        s[t] += u;
        __syncthreads();
    }
    if (i < n) rowptr[i + 1] = bexcl[blockIdx.x] + s[t];
    if (i == 0) rowptr[0] = 0;
}

__global__ void fill_kernel(const int* __restrict__ ei_src, const int* __restrict__ ei_dst,
                            const int* __restrict__ rowptr, int* __restrict__ cursor,
                            int* __restrict__ col, int E, int N) {
    int e = blockIdx.x * blockDim.x + threadIdx.x;
    int tot = E + N;
    if (e >= tot) return;
    int s, d;
    if (e < E) { s = ei_src[e]; d = ei_dst[e]; }
    else       { s = e - E;     d = s; }
    int pos = atomicAdd(&cursor[d], 1);
    col[rowptr[d] + pos] = s;   // order within a segment is irrelevant
}

// ---------------------------------------------------------------------------
// GEMM1: h = x @ W1   [N,500] x [500,64] -> [N,64]   (fp32, tiled)
// ---------------------------------------------------------------------------
__global__ __launch_bounds__(256) void gemm1_kernel(const float* __restrict__ x,
                                                    const float* __restrict__ W,
                                                    float* __restrict__ h, int n) {
    __shared__ float xs[64][20];
    __shared__ float ws[20][64];
    int row0 = blockIdx.x * 64;
    int t = threadIdx.x;
    int ty = t >> 4, tx = t & 15;
    float acc[4][4] = {};
    for (int k0 = 0; k0 < F_IN; k0 += 20) {
#pragma unroll
        for (int i = 0; i < 5; ++i) {      // 64*20 = 1280 = 5*256
            int f = t + i * 256;
            int r = f / 20, c = f - r * 20;
            int gr = row0 + r;
            xs[r][c] = (gr < n) ? x[(size_t)gr * F_IN + k0 + c] : 0.f;
        }
#pragma unroll
        for (int i = 0; i < 5; ++i) {      // 20*64 = 1280
            int f = t + i * 256;
            int r = f >> 6, c = f & 63;
            ws[r][c] = W[(k0 + r) * 64 + c];
        }
        __syncthreads();
#pragma unroll
        for (int k = 0; k < 20; ++k) {
            float a[4], b[4];
#pragma unroll
            for (int i = 0; i < 4; ++i) a[i] = xs[ty * 4 + i][k];
#pragma unroll
            for (int j = 0; j < 4; ++j) b[j] = ws[k][tx * 4 + j];
#pragma unroll
            for (int i = 0; i < 4; ++i)
#pragma unroll
                for (int j = 0; j < 4; ++j) acc[i][j] += a[i] * b[j];
        }
        __syncthreads();
    }
#pragma unroll
    for (int i = 0; i < 4; ++i) {
        int gr = row0 + ty * 4 + i;
        if (gr < n) {
            float4 v = make_float4(acc[i][0], acc[i][1], acc[i][2], acc[i][3]);
            *reinterpret_cast<float4*>(h + (size_t)gr * 64 + tx * 4) = v;
        }
    }
}

// ---------------------------------------------------------------------------
// Attention logits for layer 1:  als/ald [N,8]
// ---------------------------------------------------------------------------
__global__ void proj_al1_kernel(const float* __restrict__ h, const float* __restrict__ a1s,
                                const float* __restrict__ a1d, float* __restrict__ als,
                                float* __restrict__ ald, int n) {
    int nid = blockIdx.x * blockDim.x + threadIdx.x;
    if (nid >= n) return;
    const float* hp = h + (size_t)nid * 64;
#pragma unroll
    for (int hd = 0; hd < 8; ++hd) {
        float s = 0.f, d = 0.f;
#pragma unroll
        for (int c = 0; c < 8; ++c) {
            float hv = hp[hd * 8 + c];
            s += hv * a1s[hd * 8 + c];
            d += hv * a1d[hd * 8 + c];
        }
        als[nid * 8 + hd] = s;
        ald[nid * 8 + hd] = d;
    }
}

// ---------------------------------------------------------------------------
// GAT layer 1 edge pass: one thread per (dst, head).
// Single pass: numerator + denominator together (softmax shift-invariance,
// logits bounded so no max subtraction needed). Epilogue: /den + b1, ELU.
// ---------------------------------------------------------------------------
__global__ void gat1_edge_kernel(const int* __restrict__ rowptr, const int* __restrict__ col,
                                 const float* __restrict__ als, const float* __restrict__ ald,
                                 const float* __restrict__ h, const float* __restrict__ b1,
                                 float* __restrict__ out1, int n) {
    int tid = blockIdx.x * blockDim.x + threadIdx.x;
    int dst = tid >> 3, hd = tid & 7;
    if (dst >= n) return;
    int beg = rowptr[dst], end = rowptr[dst + 1];
    float ad = ald[dst * 8 + hd];
    float acc[8] = {};
    float den = 0.f;
    for (int j = beg; j < end; ++j) {
        int s = col[j];
        float e = als[s * 8 + hd] + ad;
        e = e > 0.f ? e : 0.2f * e;          // leaky_relu(0.2)
        float w = expf(e);
        den += w;
        const float4* hp = reinterpret_cast<const float4*>(h + (size_t)s * 64 + hd * 8);
        float4 v0 = hp[0], v1 = hp[1];
        acc[0] += w * v0.x; acc[1] += w * v0.y; acc[2] += w * v0.z; acc[3] += w * v0.w;
        acc[4] += w * v1.x; acc[5] += w * v1.y; acc[6] += w * v1.z; acc[7] += w * v1.w;
    }
    float inv = 1.f / (den + 1e-16f);
#pragma unroll
    for (int c = 0; c < 8; ++c) {
        float v = acc[c] * inv + b1[hd * 8 + c];
        v = (v > 0.f) ? v : expm1f(v);       // ELU
        out1[(size_t)dst * 64 + hd * 8 + c] = v;
    }
}

// ---------------------------------------------------------------------------
// Projection for layer 2: h2 = out1 @ W2 [N,16]; al2s/al2d scalars per node.
// ---------------------------------------------------------------------------
__global__ void proj2_kernel(const float* __restrict__ out1, const float* __restrict__ W2,
                             const float* __restrict__ a2s, const float* __restrict__ a2d,
                             float* __restrict__ h2, float* __restrict__ al2s,
                             float* __restrict__ al2d, int n) {
    int nid = blockIdx.x * blockDim.x + threadIdx.x;
    if (nid >= n) return;
    const float* op = out1 + (size_t)nid * 64;
    float acc[16] = {};
#pragma unroll 8
    for (int k = 0; k < 64; ++k) {
        float o = op[k];
#pragma unroll
        for (int c = 0; c < 16; ++c) acc[c] += o * W2[k * 16 + c];
    }
    float s = 0.f, d = 0.f;
#pragma unroll
    for (int c = 0; c < 16; ++c) {
        s += acc[c] * a2s[c];
        d += acc[c] * a2d[c];
        h2[(size_t)nid * 16 + c] = acc[c];
    }
    al2s[nid] = s;
    al2d[nid] = d;
}

// ---------------------------------------------------------------------------
// GAT layer 2 edge pass (1 head, 16 ch), fused: /den + b2, ReLU, @Wg, dinv.
// ---------------------------------------------------------------------------
__global__ void gat2_edge_kernel(const int* __restrict__ rowptr, const int* __restrict__ col,
                                 const float* __restrict__ al2s, const float* __restrict__ al2d,
                                 const float* __restrict__ h2, const float* __restrict__ b2,
                                 const float* __restrict__ Wg, float* __restrict__ xw,
                                 float* __restrict__ dinv, int n) {
    int dst = blockIdx.x * blockDim.x + threadIdx.x;
    if (dst >= n) return;
    int beg = rowptr[dst], end = rowptr[dst + 1];
    float ad = al2d[dst];
    float acc[16] = {};
    float den = 0.f;
    for (int j = beg; j < end; ++j) {
        int s = col[j];
        float e = al2s[s] + ad;
        e = e > 0.f ? e : 0.2f * e;
        float w = expf(e);
        den += w;
        const float4* hp = reinterpret_cast<const float4*>(h2 + (size_t)s * 16);
        float4 v0 = hp[0], v1 = hp[1], v2 = hp[2], v3 = hp[3];
        acc[0]  += w * v0.x; acc[1]  += w * v0.y; acc[2]  += w * v0.z; acc[3]  += w * v0.w;
        acc[4]  += w * v1.x; acc[5]  += w * v1.y; acc[6]  += w * v1.z; acc[7]  += w * v1.w;
        acc[8]  += w * v2.x; acc[9]  += w * v2.y; acc[10] += w * v2.z; acc[11] += w * v2.w;
        acc[12] += w * v3.x; acc[13] += w * v3.y; acc[14] += w * v3.z; acc[15] += w * v3.w;
    }
    float inv = 1.f / (den + 1e-16f);
    float r[16];
#pragma unroll
    for (int c = 0; c < 16; ++c) {
        float v = acc[c] * inv + b2[c];
        r[c] = (v > 0.f) ? v : 0.f;          // relu
    }
#pragma unroll
    for (int cp = 0; cp < 16; ++cp) {
        float s2 = 0.f;
#pragma unroll
        for (int c = 0; c < 16; ++c) s2 += r[c] * Wg[c * 16 + cp];
        xw[(size_t)dst * 16 + cp] = s2;
    }
    dinv[dst] = 1.f / sqrtf((float)(end - beg));   // deg >= 1 (self-loop)
}

// ---------------------------------------------------------------------------
// GCN edge pass: out = sum norm * xw[src] + bg
// ---------------------------------------------------------------------------
__global__ void gcn_kernel(const int* __restrict__ rowptr, const int* __restrict__ col,
                           const float* __restrict__ xw, const float* __restrict__ dinv,
                           const float* __restrict__ bg, float* __restrict__ out, int n) {
    int dst = blockIdx.x * blockDim.x + threadIdx.x;
    if (dst >= n) return;
    int beg = rowptr[dst], end = rowptr[dst + 1];
    float di = dinv[dst];
    float acc[16] = {};
    for (int j = beg; j < end; ++j) {
        int s = col[j];
        float nm = dinv[s] * di;
        const float4* xp = reinterpret_cast<const float4*>(xw + (size_t)s * 16);
        float4 v0 = xp[0], v1 = xp[1], v2 = xp[2], v3 = xp[3];
        acc[0]  += nm * v0.x; acc[1]  += nm * v0.y; acc[2]  += nm * v0.z; acc[3]  += nm * v0.w;
        acc[4]  += nm * v1.x; acc[5]  += nm * v1.y; acc[6]  += nm * v1.z; acc[7]  += nm * v1.w;
        acc[8]  += nm * v2.x; acc[9]  += nm * v2.y; acc[10] += nm * v2.z; acc[11] += nm * v2.w;
        acc[12] += nm * v3.x; acc[13] += nm * v3.y; acc[14] += nm * v3.z; acc[15] += nm * v3.w;
    }
#pragma unroll
    for (int c = 0; c < 16; ++c)
        out[(size_t)dst * 16 + c] = acc[c] + bg[c];
}

// ---------------------------------------------------------------------------
extern "C" void kernel_launch(void* const* d_in, const int* in_sizes, int n_in,
                              void* d_out, int out_size, void* d_ws, size_t ws_size,
                              hipStream_t stream) {
    const float* x    = (const float*)d_in[0];
    const int*   ei   = (const int*)d_in[1];     // [2,E] int
    const float* W1   = (const float*)d_in[2];
    const float* a1s  = (const float*)d_in[3];
    const float* a1d  = (const float*)d_in[4];
    const float* b1   = (const float*)d_in[5];
    const float* W2   = (const float*)d_in[6];
    const float* a2s  = (const float*)d_in[7];
    const float* a2d  = (const float*)d_in[8];
    const float* b2   = (const float*)d_in[9];
    const float* Wg   = (const float*)d_in[10];
    const float* bg   = (const float*)d_in[11];
    float* out = (float*)d_out;

    const int N = in_sizes[0] / F_IN;
    const int E = in_sizes[1] / 2;
    const int Etot = E + N;

    // ws carve-up (256B aligned regions)
    char* base = (char*)d_ws;
    size_t off = 0;
    auto alloc = [&](size_t bytes) -> char* {
        char* p = base + off;
        off = (off + bytes + 255) & ~(size_t)255;
        return p;
    };
    float* h    = (float*)alloc((size_t)N * 64 * 4);
    float* als  = (float*)alloc((size_t)N * 8 * 4);
    float* ald  = (float*)alloc((size_t)N * 8 * 4);
    float* out1 = (float*)alloc((size_t)N * 64 * 4);
    float* h2   = (float*)alloc((size_t)N * 16 * 4);
    float* al2s = (float*)alloc((size_t)N * 4);
    float* al2d = (float*)alloc((size_t)N * 4);
    float* xw   = (float*)alloc((size_t)N * 16 * 4);
    float* dinv = (float*)alloc((size_t)N * 4);
    int*   deg  = (int*)alloc((size_t)N * 4);
    int*   cur  = (int*)alloc((size_t)N * 4);
    int*   rowptr = (int*)alloc((size_t)(N + 1) * 4);
    int*   bsum = (int*)alloc(512 * 4);
    int*   bexcl= (int*)alloc(512 * 4);
    int*   col  = (int*)alloc((size_t)Etot * 4);

    const int* ei_src = ei;
    const int* ei_dst = ei + E;

    const int TB = 256;
    int nbN  = (N + TB - 1) / TB;          // 391
    int nbE  = (Etot + TB - 1) / TB;
    int nbG  = (N + 63) / 64;              // gemm blocks
    int nbA  = (N * 8 + TB - 1) / TB;      // gat1 threads

    // CSR build
    zero_int_kernel<<<nbN, TB, 0, stream>>>(deg, N);
    zero_int_kernel<<<nbN, TB, 0, stream>>>(cur, N);
    deg_kernel<<<nbE, TB, 0, stream>>>(ei_dst, deg, E, N);
    scan1_kernel<<<nbN, TB, 0, stream>>>(deg, bsum, N);
    scan2_kernel<<<1, 512, 0, stream>>>(bsum, bexcl, nbN);
    scan3_kernel<<<nbN, TB, 0, stream>>>(deg, bexcl, rowptr, N);
    fill_kernel<<<nbE, TB, 0, stream>>>(ei_src, ei_dst, rowptr, cur, col, E, N);

    // Dense pipeline
    gemm1_kernel<<<nbG, TB, 0, stream>>>(x, W1, h, N);
    proj_al1_kernel<<<nbN, TB, 0, stream>>>(h, a1s, a1d, als, ald, N);
    gat1_edge_kernel<<<nbA, TB, 0, stream>>>(rowptr, col, als, ald, h, b1, out1, N);
    proj2_kernel<<<nbN, TB, 0, stream>>>(out1, W2, a2s, a2d, h2, al2s, al2d, N);
    gat2_edge_kernel<<<nbN, TB, 0, stream>>>(rowptr, col, al2s, al2d, h2, b2, Wg, xw, dinv, N);
    gcn_kernel<<<nbN, TB, 0, stream>>>(rowptr, col, xw, dinv, bg, out, N);
}

// Round 3
// 686.161 us; speedup vs baseline: 1.1174x; 1.1174x over previous
//
#include <hip/hip_runtime.h>
#include <hip/hip_bf16.h>
#include <math.h>

// Problem constants (from reference)
#define NNODES 100000
#define F_IN   500
#define KPAD   512
#define HEADS  8
#define HID    8
#define NC     16

typedef __attribute__((ext_vector_type(8))) short bf16x8;
typedef __attribute__((ext_vector_type(4))) float f32x4;
typedef __attribute__((ext_vector_type(8))) unsigned short u16x8;

__device__ inline unsigned short f2bf_rne(float f) {
    unsigned u = __float_as_uint(f);
    u += 0x7FFF + ((u >> 16) & 1);
    return (unsigned short)(u >> 16);
}
__device__ inline float bf2f(unsigned short h) {
    return __uint_as_float(((unsigned)h) << 16);
}

// ---------------------------------------------------------------------------
// CSR build
// ---------------------------------------------------------------------------
__global__ void zero_int_kernel(int* __restrict__ p, int n) {
    int i = blockIdx.x * blockDim.x + threadIdx.x;
    if (i < n) p[i] = 0;
}

__global__ void deg_kernel(const int* __restrict__ ei_dst, int* __restrict__ deg,
                           int E, int N) {
    int e = blockIdx.x * blockDim.x + threadIdx.x;
    int tot = E + N;
    if (e >= tot) return;
    int d = (e < E) ? ei_dst[e] : (e - E);   // self-loops appended
    atomicAdd(&deg[d], 1);
}

__global__ void scan1_kernel(const int* __restrict__ deg, int* __restrict__ bsum, int n) {
    __shared__ int s[256];
    int i = blockIdx.x * 256 + threadIdx.x;
    s[threadIdx.x] = (i < n) ? deg[i] : 0;
    __syncthreads();
    for (int off = 128; off > 0; off >>= 1) {
        if (threadIdx.x < off) s[threadIdx.x] += s[threadIdx.x + off];
        __syncthreads();
    }
    if (threadIdx.x == 0) bsum[blockIdx.x] = s[0];
}

__global__ void scan2_kernel(const int* __restrict__ bsum, int* __restrict__ bexcl, int nb) {
    __shared__ int s[512];
    int t = threadIdx.x;
    int orig = (t < nb) ? bsum[t] : 0;
    s[t] = orig;
    __syncthreads();
    for (int off = 1; off < 512; off <<= 1) {
        int v = (t >= off) ? s[t - off] : 0;
        __syncthreads();
        s[t] += v;
        __syncthreads();
    }
    if (t < nb) bexcl[t] = s[t] - orig;   // exclusive
}

__global__ void scan3_kernel(const int* __restrict__ deg, const int* __restrict__ bexcl,
                             int* __restrict__ rowptr, int n) {
    __shared__ int s[256];
    int t = threadIdx.x;
    int i = blockIdx.x * 256 + t;
    int v = (i < n) ? deg[i] : 0;
    s[t] = v;
    __syncthreads();
    for (int off = 1; off < 256; off <<= 1) {
        int u = (t >= off) ? s[t - off] : 0;
        __syncthreads();
        s[t] += u;
        __syncthreads();
    }
    if (i < n) rowptr[i + 1] = bexcl[blockIdx.x] + s[t];
    if (i == 0) rowptr[0] = 0;
}

__global__ void fill_kernel(const int* __restrict__ ei_src, const int* __restrict__ ei_dst,
                            const int* __restrict__ rowptr, int* __restrict__ cursor,
                            int* __restrict__ col, int E, int N) {
    int e = blockIdx.x * blockDim.x + threadIdx.x;
    int tot = E + N;
    if (e >= tot) return;
    int s, d;
    if (e < E) { s = ei_src[e]; d = ei_dst[e]; }
    else       { s = e - E;     d = s; }
    int pos = atomicAdd(&cursor[d], 1);
    col[rowptr[d] + pos] = s;   // order within a segment is irrelevant
}

// ---------------------------------------------------------------------------
// W1 transpose + zero-pad: Wt[c][k] = (k<500) ? W1[k][c] : 0, Wt is [64][512]
// ---------------------------------------------------------------------------
__global__ void transposeW1_kernel(const float* __restrict__ W, float* __restrict__ Wt) {
    int i = blockIdx.x * blockDim.x + threadIdx.x;   // 64*512 threads
    if (i >= 64 * KPAD) return;
    int c = i >> 9;        // 0..63
    int k = i & (KPAD - 1);
    Wt[i] = (k < F_IN) ? W[k * 64 + c] : 0.f;
}

// ---------------------------------------------------------------------------
// GEMM1 via split-bf16 MFMA: h = x @ W1  [N,500]x[500,64] -> [N,64]
// x = hi + lo (bf16 each); A*B ~= Ah*Bh + Ah*Bl + Al*Bh  (fp32-accurate)
// Tile: 128 rows x 64 cols, 4 waves (each 32x64), BK=32, 16x16x32 MFMA.
// ---------------------------------------------------------------------------
#define BM  128
#define BK  32
#define LDT 40   // padded LDS stride in bf16 elems (16B-aligned rows, ~2-way bank)

__global__ __launch_bounds__(256) void gemm1_mfma_kernel(
        const float* __restrict__ x, const float* __restrict__ Wt,
        float* __restrict__ h, int n) {
    __shared__ unsigned short sAh[BM * LDT];
    __shared__ unsigned short sAl[BM * LDT];
    __shared__ unsigned short sBh[64 * LDT];
    __shared__ unsigned short sBl[64 * LDT];

    int t = threadIdx.x;
    int wave = t >> 6, lane = t & 63;
    int l15 = lane & 15, kgrp = lane >> 4;
    int row0 = blockIdx.x * BM;
    int wrow0 = wave * 32;

    // staging coords: A: 128 rows x 32 k-cols (16 floats/thread)
    int ar = t >> 1;
    int ak = (t & 1) * 16;
    // B: 64 rows(cols of W) x 32 k-cols (8 floats/thread)
    int bc = t >> 2;
    int bk = (t & 3) * 8;

    f32x4 acc[2][4];
#pragma unroll
    for (int m = 0; m < 2; ++m)
#pragma unroll
        for (int nn = 0; nn < 4; ++nn)
            acc[m][nn] = (f32x4){0.f, 0.f, 0.f, 0.f};

    const int gr = row0 + ar;

    for (int k0 = 0; k0 < KPAD; k0 += BK) {
        // ---- stage A (x tile), fp32 -> bf16 hi/lo
        float av[16];
        if (gr < n) {
            if (k0 + BK <= F_IN) {
                const float4* p = (const float4*)(x + (size_t)gr * F_IN + k0 + ak);
                float4 q0 = p[0], q1 = p[1], q2 = p[2], q3 = p[3];
                av[0]=q0.x; av[1]=q0.y; av[2]=q0.z; av[3]=q0.w;
                av[4]=q1.x; av[5]=q1.y; av[6]=q1.z; av[7]=q1.w;
                av[8]=q2.x; av[9]=q2.y; av[10]=q2.z; av[11]=q2.w;
                av[12]=q3.x; av[13]=q3.y; av[14]=q3.z; av[15]=q3.w;
            } else {
#pragma unroll
                for (int j = 0; j < 16; ++j) {
                    int kk = k0 + ak + j;
                    av[j] = (kk < F_IN) ? x[(size_t)gr * F_IN + kk] : 0.f;
                }
            }
        } else {
#pragma unroll
            for (int j = 0; j < 16; ++j) av[j] = 0.f;
        }
        u16x8 ah0, ah1, al0, al1;
#pragma unroll
        for (int j = 0; j < 8; ++j) {
            unsigned short hi = f2bf_rne(av[j]);
            ah0[j] = hi;
            al0[j] = f2bf_rne(av[j] - bf2f(hi));
        }
#pragma unroll
        for (int j = 0; j < 8; ++j) {
            unsigned short hi = f2bf_rne(av[8 + j]);
            ah1[j] = hi;
            al1[j] = f2bf_rne(av[8 + j] - bf2f(hi));
        }
        *(u16x8*)&sAh[ar * LDT + ak]     = ah0;
        *(u16x8*)&sAh[ar * LDT + ak + 8] = ah1;
        *(u16x8*)&sAl[ar * LDT + ak]     = al0;
        *(u16x8*)&sAl[ar * LDT + ak + 8] = al1;

        // ---- stage B (Wt tile: [64][32] slice, already transposed+padded)
        const float4* bp = (const float4*)(Wt + (size_t)bc * KPAD + k0 + bk);
        float4 w0 = bp[0], w1 = bp[1];
        float bv[8] = {w0.x, w0.y, w0.z, w0.w, w1.x, w1.y, w1.z, w1.w};
        u16x8 bh, bl;
#pragma unroll
        for (int j = 0; j < 8; ++j) {
            unsigned short hi = f2bf_rne(bv[j]);
            bh[j] = hi;
            bl[j] = f2bf_rne(bv[j] - bf2f(hi));
        }
        *(u16x8*)&sBh[bc * LDT + bk] = bh;
        *(u16x8*)&sBl[bc * LDT + bk] = bl;

        __syncthreads();

        // ---- MFMA compute
        bf16x8 aH[2], aL[2], bH[4], bL[4];
#pragma unroll
        for (int m = 0; m < 2; ++m) {
            int r = wrow0 + m * 16 + l15;
            aH[m] = *(const bf16x8*)&sAh[r * LDT + kgrp * 8];
            aL[m] = *(const bf16x8*)&sAl[r * LDT + kgrp * 8];
        }
#pragma unroll
        for (int nn = 0; nn < 4; ++nn) {
            int c = nn * 16 + l15;
            bH[nn] = *(const bf16x8*)&sBh[c * LDT + kgrp * 8];
            bL[nn] = *(const bf16x8*)&sBl[c * LDT + kgrp * 8];
        }
#pragma unroll
        for (int m = 0; m < 2; ++m)
#pragma unroll
            for (int nn = 0; nn < 4; ++nn) {
                acc[m][nn] = __builtin_amdgcn_mfma_f32_16x16x32_bf16(aH[m], bH[nn], acc[m][nn], 0, 0, 0);
                acc[m][nn] = __builtin_amdgcn_mfma_f32_16x16x32_bf16(aH[m], bL[nn], acc[m][nn], 0, 0, 0);
                acc[m][nn] = __builtin_amdgcn_mfma_f32_16x16x32_bf16(aL[m], bH[nn], acc[m][nn], 0, 0, 0);
            }
        __syncthreads();
    }

    // ---- epilogue: D row=(lane>>4)*4+reg, col=lane&15
#pragma unroll
    for (int m = 0; m < 2; ++m) {
#pragma unroll
        for (int nn = 0; nn < 4; ++nn) {
#pragma unroll
            for (int r = 0; r < 4; ++r) {
                int row = row0 + wrow0 + m * 16 + kgrp * 4 + r;
                if (row < n)
                    h[(size_t)row * 64 + nn * 16 + l15] = acc[m][nn][r];
            }
        }
    }
}

// ---------------------------------------------------------------------------
// Attention logits for layer 1:  als/ald [N,8]
// ---------------------------------------------------------------------------
__global__ void proj_al1_kernel(const float* __restrict__ h, const float* __restrict__ a1s,
                                const float* __restrict__ a1d, float* __restrict__ als,
                                float* __restrict__ ald, int n) {
    int nid = blockIdx.x * blockDim.x + threadIdx.x;
    if (nid >= n) return;
    const float* hp = h + (size_t)nid * 64;
#pragma unroll
    for (int hd = 0; hd < 8; ++hd) {
        float s = 0.f, d = 0.f;
#pragma unroll
        for (int c = 0; c < 8; ++c) {
            float hv = hp[hd * 8 + c];
            s += hv * a1s[hd * 8 + c];
            d += hv * a1d[hd * 8 + c];
        }
        als[nid * 8 + hd] = s;
        ald[nid * 8 + hd] = d;
    }
}

// ---------------------------------------------------------------------------
// GAT layer 1 edge pass: one thread per (dst, head).
// ---------------------------------------------------------------------------
__global__ void gat1_edge_kernel(const int* __restrict__ rowptr, const int* __restrict__ col,
                                 const float* __restrict__ als, const float* __restrict__ ald,
                                 const float* __restrict__ h, const float* __restrict__ b1,
                                 float* __restrict__ out1, int n) {
    int tid = blockIdx.x * blockDim.x + threadIdx.x;
    int dst = tid >> 3, hd = tid & 7;
    if (dst >= n) return;
    int beg = rowptr[dst], end = rowptr[dst + 1];
    float ad = ald[dst * 8 + hd];
    float acc[8] = {};
    float den = 0.f;
    for (int j = beg; j < end; ++j) {
        int s = col[j];
        float e = als[s * 8 + hd] + ad;
        e = e > 0.f ? e : 0.2f * e;          // leaky_relu(0.2)
        float w = expf(e);
        den += w;
        const float4* hp = reinterpret_cast<const float4*>(h + (size_t)s * 64 + hd * 8);
        float4 v0 = hp[0], v1 = hp[1];
        acc[0] += w * v0.x; acc[1] += w * v0.y; acc[2] += w * v0.z; acc[3] += w * v0.w;
        acc[4] += w * v1.x; acc[5] += w * v1.y; acc[6] += w * v1.z; acc[7] += w * v1.w;
    }
    float inv = 1.f / (den + 1e-16f);
#pragma unroll
    for (int c = 0; c < 8; ++c) {
        float v = acc[c] * inv + b1[hd * 8 + c];
        v = (v > 0.f) ? v : expm1f(v);       // ELU
        out1[(size_t)dst * 64 + hd * 8 + c] = v;
    }
}

// ---------------------------------------------------------------------------
// Projection for layer 2: h2 = out1 @ W2 [N,16]; al2s/al2d scalars per node.
// ---------------------------------------------------------------------------
__global__ void proj2_kernel(const float* __restrict__ out1, const float* __restrict__ W2,
                             const float* __restrict__ a2s, const float* __restrict__ a2d,
                             float* __restrict__ h2, float* __restrict__ al2s,
                             float* __restrict__ al2d, int n) {
    int nid = blockIdx.x * blockDim.x + threadIdx.x;
    if (nid >= n) return;
    const float* op = out1 + (size_t)nid * 64;
    float acc[16] = {};
#pragma unroll 8
    for (int k = 0; k < 64; ++k) {
        float o = op[k];
#pragma unroll
        for (int c = 0; c < 16; ++c) acc[c] += o * W2[k * 16 + c];
    }
    float s = 0.f, d = 0.f;
#pragma unroll
    for (int c = 0; c < 16; ++c) {
        s += acc[c] * a2s[c];
        d += acc[c] * a2d[c];
        h2[(size_t)nid * 16 + c] = acc[c];
    }
    al2s[nid] = s;
    al2d[nid] = d;
}

// ---------------------------------------------------------------------------
// GAT layer 2 edge pass (1 head, 16 ch), fused: /den + b2, ReLU, @Wg, dinv.
// ---------------------------------------------------------------------------
__global__ void gat2_edge_kernel(const int* __restrict__ rowptr, const int* __restrict__ col,
                                 const float* __restrict__ al2s, const float* __restrict__ al2d,
                                 const float* __restrict__ h2, const float* __restrict__ b2,
                                 const float* __restrict__ Wg, float* __restrict__ xw,
                                 float* __restrict__ dinv, int n) {
    int dst = blockIdx.x * blockDim.x + threadIdx.x;
    if (dst >= n) return;
    int beg = rowptr[dst], end = rowptr[dst + 1];
    float ad = al2d[dst];
    float acc[16] = {};
    float den = 0.f;
    for (int j = beg; j < end; ++j) {
        int s = col[j];
        float e = al2s[s] + ad;
        e = e > 0.f ? e : 0.2f * e;
        float w = expf(e);
        den += w;
        const float4* hp = reinterpret_cast<const float4*>(h2 + (size_t)s * 16);
        float4 v0 = hp[0], v1 = hp[1], v2 = hp[2], v3 = hp[3];
        acc[0]  += w * v0.x; acc[1]  += w * v0.y; acc[2]  += w * v0.z; acc[3]  += w * v0.w;
        acc[4]  += w * v1.x; acc[5]  += w * v1.y; acc[6]  += w * v1.z; acc[7]  += w * v1.w;
        acc[8]  += w * v2.x; acc[9]  += w * v2.y; acc[10] += w * v2.z; acc[11] += w * v2.w;
        acc[12] += w * v3.x; acc[13] += w * v3.y; acc[14] += w * v3.z; acc[15] += w * v3.w;
    }
    float inv = 1.f / (den + 1e-16f);
    float r[16];
#pragma unroll
    for (int c = 0; c < 16; ++c) {
        float v = acc[c] * inv + b2[c];
        r[c] = (v > 0.f) ? v : 0.f;          // relu
    }
#pragma unroll
    for (int cp = 0; cp < 16; ++cp) {
        float s2 = 0.f;
#pragma unroll
        for (int c = 0; c < 16; ++c) s2 += r[c] * Wg[c * 16 + cp];
        xw[(size_t)dst * 16 + cp] = s2;
    }
    dinv[dst] = 1.f / sqrtf((float)(end - beg));   // deg >= 1 (self-loop)
}

// ---------------------------------------------------------------------------
// GCN edge pass: out = sum norm * xw[src] + bg
// ---------------------------------------------------------------------------
__global__ void gcn_kernel(const int* __restrict__ rowptr, const int* __restrict__ col,
                           const float* __restrict__ xw, const float* __restrict__ dinv,
                           const float* __restrict__ bg, float* __restrict__ out, int n) {
    int dst = blockIdx.x * blockDim.x + threadIdx.x;
    if (dst >= n) return;
    int beg = rowptr[dst], end = rowptr[dst + 1];
    float di = dinv[dst];
    float acc[16] = {};
    for (int j = beg; j < end; ++j) {
        int s = col[j];
        float nm = dinv[s] * di;
        const float4* xp = reinterpret_cast<const float4*>(xw + (size_t)s * 16);
        float4 v0 = xp[0], v1 = xp[1], v2 = xp[2], v3 = xp[3];
        acc[0]  += nm * v0.x; acc[1]  += nm * v0.y; acc[2]  += nm * v0.z; acc[3]  += nm * v0.w;
        acc[4]  += nm * v1.x; acc[5]  += nm * v1.y; acc[6]  += nm * v1.z; acc[7]  += nm * v1.w;
        acc[8]  += nm * v2.x; acc[9]  += nm * v2.y; acc[10] += nm * v2.z; acc[11] += nm * v2.w;
        acc[12] += nm * v3.x; acc[13] += nm * v3.y; acc[14] += nm * v3.z; acc[15] += nm * v3.w;
    }
#pragma unroll
    for (int c = 0; c < 16; ++c)
        out[(size_t)dst * 16 + c] = acc[c] + bg[c];
}

// ---------------------------------------------------------------------------
extern "C" void kernel_launch(void* const* d_in, const int* in_sizes, int n_in,
                              void* d_out, int out_size, void* d_ws, size_t ws_size,
                              hipStream_t stream) {
    const float* x    = (const float*)d_in[0];
    const int*   ei   = (const int*)d_in[1];     // [2,E] int
    const float* W1   = (const float*)d_in[2];
    const float* a1s  = (const float*)d_in[3];
    const float* a1d  = (const float*)d_in[4];
    const float* b1   = (const float*)d_in[5];
    const float* W2   = (const float*)d_in[6];
    const float* a2s  = (const float*)d_in[7];
    const float* a2d  = (const float*)d_in[8];
    const float* b2   = (const float*)d_in[9];
    const float* Wg   = (const float*)d_in[10];
    const float* bg   = (const float*)d_in[11];
    float* out = (float*)d_out;

    const int N = in_sizes[0] / F_IN;
    const int E = in_sizes[1] / 2;
    const int Etot = E + N;

    // ws carve-up (256B aligned regions)
    char* base = (char*)d_ws;
    size_t off = 0;
    auto alloc = [&](size_t bytes) -> char* {
        char* p = base + off;
        off = (off + bytes + 255) & ~(size_t)255;
        return p;
    };
    float* h    = (float*)alloc((size_t)N * 64 * 4);
    float* als  = (float*)alloc((size_t)N * 8 * 4);
    float* ald  = (float*)alloc((size_t)N * 8 * 4);
    float* out1 = (float*)alloc((size_t)N * 64 * 4);
    float* h2   = (float*)alloc((size_t)N * 16 * 4);
    float* al2s = (float*)alloc((size_t)N * 4);
    float* al2d = (float*)alloc((size_t)N * 4);
    float* xw   = (float*)alloc((size_t)N * 16 * 4);
    float* dinv = (float*)alloc((size_t)N * 4);
    int*   deg  = (int*)alloc((size_t)N * 4);
    int*   cur  = (int*)alloc((size_t)N * 4);
    int*   rowptr = (int*)alloc((size_t)(N + 1) * 4);
    int*   bsum = (int*)alloc(512 * 4);
    int*   bexcl= (int*)alloc(512 * 4);
    int*   col  = (int*)alloc((size_t)Etot * 4);
    float* Wt   = (float*)alloc((size_t)64 * KPAD * 4);   // transposed+padded W1

    const int* ei_src = ei;
    const int* ei_dst = ei + E;

    const int TB = 256;
    int nbN  = (N + TB - 1) / TB;          // 391
    int nbE  = (Etot + TB - 1) / TB;
    int nbG  = (N + BM - 1) / BM;          // mfma gemm blocks (782)
    int nbA  = (N * 8 + TB - 1) / TB;      // gat1 threads

    // CSR build
    zero_int_kernel<<<nbN, TB, 0, stream>>>(deg, N);
    zero_int_kernel<<<nbN, TB, 0, stream>>>(cur, N);
    deg_kernel<<<nbE, TB, 0, stream>>>(ei_dst, deg, E, N);
    scan1_kernel<<<nbN, TB, 0, stream>>>(deg, bsum, N);
    scan2_kernel<<<1, 512, 0, stream>>>(bsum, bexcl, nbN);
    scan3_kernel<<<nbN, TB, 0, stream>>>(deg, bexcl, rowptr, N);
    fill_kernel<<<nbE, TB, 0, stream>>>(ei_src, ei_dst, rowptr, cur, col, E, N);

    // Dense pipeline
    transposeW1_kernel<<<(64 * KPAD + TB - 1) / TB, TB, 0, stream>>>(W1, Wt);
    gemm1_mfma_kernel<<<nbG, TB, 0, stream>>>(x, Wt, h, N);
    proj_al1_kernel<<<nbN, TB, 0, stream>>>(h, a1s, a1d, als, ald, N);
    gat1_edge_kernel<<<nbA, TB, 0, stream>>>(rowptr, col, als, ald, h, b1, out1, N);
    proj2_kernel<<<nbN, TB, 0, stream>>>(out1, W2, a2s, a2d, h2, al2s, al2d, N);
    gat2_edge_kernel<<<nbN, TB, 0, stream>>>(rowptr, col, al2s, al2d, h2, b2, Wg, xw, dinv, N);
    gcn_kernel<<<nbN, TB, 0, stream>>>(rowptr, col, xw, dinv, bg, out, N);
}

// Round 6
// 665.744 us; speedup vs baseline: 1.1517x; 1.0307x over previous
//
#include <hip/hip_runtime.h>
#include <hip/hip_bf16.h>
#include <math.h>

// Problem constants (from reference)
#define NNODES 100000
#define F_IN   500
#define KPAD   512
#define HEADS  8
#define HID    8
#define NC     16

typedef __attribute__((ext_vector_type(8))) short bf16x8;
typedef __attribute__((ext_vector_type(4))) float f32x4;
typedef __attribute__((ext_vector_type(8))) unsigned short u16x8;

__device__ inline unsigned short f2bf_rne(float f) {
    unsigned u = __float_as_uint(f);
    u += 0x7FFF + ((u >> 16) & 1);
    return (unsigned short)(u >> 16);
}
__device__ inline float bf2f(unsigned short h) {
    return __uint_as_float(((unsigned)h) << 16);
}

// ---------------------------------------------------------------------------
// CSR build
// ---------------------------------------------------------------------------
__global__ void zero_int_kernel(int* __restrict__ p, int n) {
    int i = blockIdx.x * blockDim.x + threadIdx.x;
    if (i < n) p[i] = 0;
}

// Degree + per-edge position in one pass: pos[e] = atomicAdd(&deg[d],1).
// 4 edges per thread, int4 loads on the aligned fast path.
__global__ void deg_pos_kernel(const int* __restrict__ ei_dst, int* __restrict__ deg,
                               int* __restrict__ pos, int E, int N) {
    int tot = E + N;
    int i0 = (blockIdx.x * blockDim.x + threadIdx.x) * 4;
    if (i0 >= tot) return;
    if (i0 + 3 < E) {
        int4 d4 = *reinterpret_cast<const int4*>(ei_dst + i0);
        int p0 = atomicAdd(&deg[d4.x], 1);
        int p1 = atomicAdd(&deg[d4.y], 1);
        int p2 = atomicAdd(&deg[d4.z], 1);
        int p3 = atomicAdd(&deg[d4.w], 1);
        *reinterpret_cast<int4*>(pos + i0) = make_int4(p0, p1, p2, p3);
    } else {
#pragma unroll
        for (int j = 0; j < 4; ++j) {
            int e = i0 + j;
            if (e >= tot) break;
            int d = (e < E) ? ei_dst[e] : (e - E);
            pos[e] = atomicAdd(&deg[d], 1);
        }
    }
}

__global__ void scan1_kernel(const int* __restrict__ deg, int* __restrict__ bsum, int n) {
    __shared__ int s[256];
    int i = blockIdx.x * 256 + threadIdx.x;
    s[threadIdx.x] = (i < n) ? deg[i] : 0;
    __syncthreads();
    for (int off = 128; off > 0; off >>= 1) {
        if (threadIdx.x < off) s[threadIdx.x] += s[threadIdx.x + off];
        __syncthreads();
    }
    if (threadIdx.x == 0) bsum[blockIdx.x] = s[0];
}

__global__ void scan2_kernel(const int* __restrict__ bsum, int* __restrict__ bexcl, int nb) {
    __shared__ int s[512];
    int t = threadIdx.x;
    int orig = (t < nb) ? bsum[t] : 0;
    s[t] = orig;
    __syncthreads();
    for (int off = 1; off < 512; off <<= 1) {
        int v = (t >= off) ? s[t - off] : 0;
        __syncthreads();
        s[t] += v;
        __syncthreads();
    }
    if (t < nb) bexcl[t] = s[t] - orig;   // exclusive
}

__global__ void scan3_kernel(const int* __restrict__ deg, const int* __restrict__ bexcl,
                             int* __restrict__ rowptr, int n) {
    __shared__ int s[256];
    int t = threadIdx.x;
    int i = blockIdx.x * 256 + t;
    int v = (i < n) ? deg[i] : 0;
    s[t] = v;
    __syncthreads();
    for (int off = 1; off < 256; off <<= 1) {
        int u = (t >= off) ? s[t - off] : 0;
        __syncthreads();
        s[t] += u;
        __syncthreads();
    }
    if (i < n) rowptr[i + 1] = bexcl[blockIdx.x] + s[t];
    if (i == 0) rowptr[0] = 0;
}

// Atomic-free fill: col[rowptr[d] + pos[e]] = s, nt scatter store.
__global__ void fill2_kernel(const int* __restrict__ ei_src, const int* __restrict__ ei_dst,
                             const int* __restrict__ rowptr, const int* __restrict__ pos,
                             int* __restrict__ col, int E, int N) {
    int tot = E + N;
    int i0 = (blockIdx.x * blockDim.x + threadIdx.x) * 4;
    if (i0 >= tot) return;
    if (i0 + 3 < E) {
        int4 s4 = *reinterpret_cast<const int4*>(ei_src + i0);
        int4 d4 = *reinterpret_cast<const int4*>(ei_dst + i0);
        int4 p4 = *reinterpret_cast<const int4*>(pos + i0);
        int o0 = rowptr[d4.x] + p4.x;
        int o1 = rowptr[d4.y] + p4.y;
        int o2 = rowptr[d4.z] + p4.z;
        int o3 = rowptr[d4.w] + p4.w;
        __builtin_nontemporal_store(s4.x, &col[o0]);
        __builtin_nontemporal_store(s4.y, &col[o1]);
        __builtin_nontemporal_store(s4.z, &col[o2]);
        __builtin_nontemporal_store(s4.w, &col[o3]);
    } else {
#pragma unroll
        for (int j = 0; j < 4; ++j) {
            int e = i0 + j;
            if (e >= tot) break;
            int s, d;
            if (e < E) { s = ei_src[e]; d = ei_dst[e]; }
            else       { s = e - E;     d = s; }
            __builtin_nontemporal_store(s, &col[rowptr[d] + pos[e]]);
        }
    }
}

// ---------------------------------------------------------------------------
// W1 transpose + zero-pad: Wt[c][k] = (k<500) ? W1[k][c] : 0, Wt is [64][512]
// ---------------------------------------------------------------------------
__global__ void transposeW1_kernel(const float* __restrict__ W, float* __restrict__ Wt) {
    int i = blockIdx.x * blockDim.x + threadIdx.x;   // 64*512 threads
    if (i >= 64 * KPAD) return;
    int c = i >> 9;        // 0..63
    int k = i & (KPAD - 1);
    Wt[i] = (k < F_IN) ? W[k * 64 + c] : 0.f;
}

// ---------------------------------------------------------------------------
// GEMM1 via split-bf16 MFMA: h = x @ W1  [N,500]x[500,64] -> [N,64]
// x = hi + lo (bf16 each); A*B ~= Ah*Bh + Ah*Bl + Al*Bh  (fp32-accurate)
// Tile: 128 rows x 64 cols, 4 waves (each 32x64), BK=32, 16x16x32 MFMA.
// ---------------------------------------------------------------------------
#define BM  128
#define BK  32
#define LDT 40   // padded LDS stride in bf16 elems (16B-aligned rows, ~2-way bank)

__global__ __launch_bounds__(256) void gemm1_mfma_kernel(
        const float* __restrict__ x, const float* __restrict__ Wt,
        float* __restrict__ h, int n) {
    __shared__ unsigned short sAh[BM * LDT];
    __shared__ unsigned short sAl[BM * LDT];
    __shared__ unsigned short sBh[64 * LDT];
    __shared__ unsigned short sBl[64 * LDT];

    int t = threadIdx.x;
    int wave = t >> 6, lane = t & 63;
    int l15 = lane & 15, kgrp = lane >> 4;
    int row0 = blockIdx.x * BM;
    int wrow0 = wave * 32;

    // staging coords: A: 128 rows x 32 k-cols (16 floats/thread)
    int ar = t >> 1;
    int ak = (t & 1) * 16;
    // B: 64 rows(cols of W) x 32 k-cols (8 floats/thread)
    int bc = t >> 2;
    int bk = (t & 3) * 8;

    f32x4 acc[2][4];
#pragma unroll
    for (int m = 0; m < 2; ++m)
#pragma unroll
        for (int nn = 0; nn < 4; ++nn)
            acc[m][nn] = (f32x4){0.f, 0.f, 0.f, 0.f};

    const int gr = row0 + ar;

    for (int k0 = 0; k0 < KPAD; k0 += BK) {
        // ---- stage A (x tile), fp32 -> bf16 hi/lo
        float av[16];
        if (gr < n) {
            if (k0 + BK <= F_IN) {
                const float4* p = (const float4*)(x + (size_t)gr * F_IN + k0 + ak);
                float4 q0 = p[0], q1 = p[1], q2 = p[2], q3 = p[3];
                av[0]=q0.x; av[1]=q0.y; av[2]=q0.z; av[3]=q0.w;
                av[4]=q1.x; av[5]=q1.y; av[6]=q1.z; av[7]=q1.w;
                av[8]=q2.x; av[9]=q2.y; av[10]=q2.z; av[11]=q2.w;
                av[12]=q3.x; av[13]=q3.y; av[14]=q3.z; av[15]=q3.w;
            } else {
#pragma unroll
                for (int j = 0; j < 16; ++j) {
                    int kk = k0 + ak + j;
                    av[j] = (kk < F_IN) ? x[(size_t)gr * F_IN + kk] : 0.f;
                }
            }
        } else {
#pragma unroll
            for (int j = 0; j < 16; ++j) av[j] = 0.f;
        }
        u16x8 ah0, ah1, al0, al1;
#pragma unroll
        for (int j = 0; j < 8; ++j) {
            unsigned short hi = f2bf_rne(av[j]);
            ah0[j] = hi;
            al0[j] = f2bf_rne(av[j] - bf2f(hi));
        }
#pragma unroll
        for (int j = 0; j < 8; ++j) {
            unsigned short hi = f2bf_rne(av[8 + j]);
            ah1[j] = hi;
            al1[j] = f2bf_rne(av[8 + j] - bf2f(hi));
        }
        *(u16x8*)&sAh[ar * LDT + ak]     = ah0;
        *(u16x8*)&sAh[ar * LDT + ak + 8] = ah1;
        *(u16x8*)&sAl[ar * LDT + ak]     = al0;
        *(u16x8*)&sAl[ar * LDT + ak + 8] = al1;

        // ---- stage B (Wt tile: [64][32] slice, already transposed+padded)
        const float4* bp = (const float4*)(Wt + (size_t)bc * KPAD + k0 + bk);
        float4 w0 = bp[0], w1 = bp[1];
        float bv[8] = {w0.x, w0.y, w0.z, w0.w, w1.x, w1.y, w1.z, w1.w};
        u16x8 bh, bl;
#pragma unroll
        for (int j = 0; j < 8; ++j) {
            unsigned short hi = f2bf_rne(bv[j]);
            bh[j] = hi;
            bl[j] = f2bf_rne(bv[j] - bf2f(hi));
        }
        *(u16x8*)&sBh[bc * LDT + bk] = bh;
        *(u16x8*)&sBl[bc * LDT + bk] = bl;

        __syncthreads();

        // ---- MFMA compute
        bf16x8 aH[2], aL[2], bH[4], bL[4];
#pragma unroll
        for (int m = 0; m < 2; ++m) {
            int r = wrow0 + m * 16 + l15;
            aH[m] = *(const bf16x8*)&sAh[r * LDT + kgrp * 8];
            aL[m] = *(const bf16x8*)&sAl[r * LDT + kgrp * 8];
        }
#pragma unroll
        for (int nn = 0; nn < 4; ++nn) {
            int c = nn * 16 + l15;
            bH[nn] = *(const bf16x8*)&sBh[c * LDT + kgrp * 8];
            bL[nn] = *(const bf16x8*)&sBl[c * LDT + kgrp * 8];
        }
#pragma unroll
        for (int m = 0; m < 2; ++m)
#pragma unroll
            for (int nn = 0; nn < 4; ++nn) {
                acc[m][nn] = __builtin_amdgcn_mfma_f32_16x16x32_bf16(aH[m], bH[nn], acc[m][nn], 0, 0, 0);
                acc[m][nn] = __builtin_amdgcn_mfma_f32_16x16x32_bf16(aH[m], bL[nn], acc[m][nn], 0, 0, 0);
                acc[m][nn] = __builtin_amdgcn_mfma_f32_16x16x32_bf16(aL[m], bH[nn], acc[m][nn], 0, 0, 0);
            }
        __syncthreads();
    }

    // ---- epilogue: D row=(lane>>4)*4+reg, col=lane&15
#pragma unroll
    for (int m = 0; m < 2; ++m) {
#pragma unroll
        for (int nn = 0; nn < 4; ++nn) {
#pragma unroll
            for (int r = 0; r < 4; ++r) {
                int row = row0 + wrow0 + m * 16 + kgrp * 4 + r;
                if (row < n)
                    h[(size_t)row * 64 + nn * 16 + l15] = acc[m][nn][r];
            }
        }
    }
}

// ---------------------------------------------------------------------------
// Attention logits for layer 1:  als/ald [N,8]
// ---------------------------------------------------------------------------
__global__ void proj_al1_kernel(const float* __restrict__ h, const float* __restrict__ a1s,
                                const float* __restrict__ a1d, float* __restrict__ als,
                                float* __restrict__ ald, int n) {
    int nid = blockIdx.x * blockDim.x + threadIdx.x;
    if (nid >= n) return;
    const float* hp = h + (size_t)nid * 64;
#pragma unroll
    for (int hd = 0; hd < 8; ++hd) {
        float s = 0.f, d = 0.f;
#pragma unroll
        for (int c = 0; c < 8; ++c) {
            float hv = hp[hd * 8 + c];
            s += hv * a1s[hd * 8 + c];
            d += hv * a1d[hd * 8 + c];
        }
        als[nid * 8 + hd] = s;
        ald[nid * 8 + hd] = d;
    }
}

// ---------------------------------------------------------------------------
// GAT layer 1 edge pass: one thread per (dst, head).
// ---------------------------------------------------------------------------
__global__ void gat1_edge_kernel(const int* __restrict__ rowptr, const int* __restrict__ col,
                                 const float* __restrict__ als, const float* __restrict__ ald,
                                 const float* __restrict__ h, const float* __restrict__ b1,
                                 float* __restrict__ out1, int n) {
    int tid = blockIdx.x * blockDim.x + threadIdx.x;
    int dst = tid >> 3, hd = tid & 7;
    if (dst >= n) return;
    int beg = rowptr[dst], end = rowptr[dst + 1];
    float ad = ald[dst * 8 + hd];
    float acc[8] = {};
    float den = 0.f;
    for (int j = beg; j < end; ++j) {
        int s = col[j];
        float e = als[s * 8 + hd] + ad;
        e = e > 0.f ? e : 0.2f * e;          // leaky_relu(0.2)
        float w = expf(e);
        den += w;
        const float4* hp = reinterpret_cast<const float4*>(h + (size_t)s * 64 + hd * 8);
        float4 v0 = hp[0], v1 = hp[1];
        acc[0] += w * v0.x; acc[1] += w * v0.y; acc[2] += w * v0.z; acc[3] += w * v0.w;
        acc[4] += w * v1.x; acc[5] += w * v1.y; acc[6] += w * v1.z; acc[7] += w * v1.w;
    }
    float inv = 1.f / (den + 1e-16f);
#pragma unroll
    for (int c = 0; c < 8; ++c) {
        float v = acc[c] * inv + b1[hd * 8 + c];
        v = (v > 0.f) ? v : expm1f(v);       // ELU
        out1[(size_t)dst * 64 + hd * 8 + c] = v;
    }
}

// ---------------------------------------------------------------------------
// Projection for layer 2: h2 = out1 @ W2 [N,16]; al2s/al2d scalars per node.
// ---------------------------------------------------------------------------
__global__ void proj2_kernel(const float* __restrict__ out1, const float* __restrict__ W2,
                             const float* __restrict__ a2s, const float* __restrict__ a2d,
                             float* __restrict__ h2, float* __restrict__ al2s,
                             float* __restrict__ al2d, int n) {
    int nid = blockIdx.x * blockDim.x + threadIdx.x;
    if (nid >= n) return;
    const float* op = out1 + (size_t)nid * 64;
    float acc[16] = {};
#pragma unroll 8
    for (int k = 0; k < 64; ++k) {
        float o = op[k];
#pragma unroll
        for (int c = 0; c < 16; ++c) acc[c] += o * W2[k * 16 + c];
    }
    float s = 0.f, d = 0.f;
#pragma unroll
    for (int c = 0; c < 16; ++c) {
        s += acc[c] * a2s[c];
        d += acc[c] * a2d[c];
        h2[(size_t)nid * 16 + c] = acc[c];
    }
    al2s[nid] = s;
    al2d[nid] = d;
}

// ---------------------------------------------------------------------------
// GAT layer 2 edge pass (1 head, 16 ch), fused: /den + b2, ReLU, @Wg, dinv.
// ---------------------------------------------------------------------------
__global__ void gat2_edge_kernel(const int* __restrict__ rowptr, const int* __restrict__ col,
                                 const float* __restrict__ al2s, const float* __restrict__ al2d,
                                 const float* __restrict__ h2, const float* __restrict__ b2,
                                 const float* __restrict__ Wg, float* __restrict__ xw,
                                 float* __restrict__ dinv, int n) {
    int dst = blockIdx.x * blockDim.x + threadIdx.x;
    if (dst >= n) return;
    int beg = rowptr[dst], end = rowptr[dst + 1];
    float ad = al2d[dst];
    float acc[16] = {};
    float den = 0.f;
    for (int j = beg; j < end; ++j) {
        int s = col[j];
        float e = al2s[s] + ad;
        e = e > 0.f ? e : 0.2f * e;
        float w = expf(e);
        den += w;
        const float4* hp = reinterpret_cast<const float4*>(h2 + (size_t)s * 16);
        float4 v0 = hp[0], v1 = hp[1], v2 = hp[2], v3 = hp[3];
        acc[0]  += w * v0.x; acc[1]  += w * v0.y; acc[2]  += w * v0.z; acc[3]  += w * v0.w;
        acc[4]  += w * v1.x; acc[5]  += w * v1.y; acc[6]  += w * v1.z; acc[7]  += w * v1.w;
        acc[8]  += w * v2.x; acc[9]  += w * v2.y; acc[10] += w * v2.z; acc[11] += w * v2.w;
        acc[12] += w * v3.x; acc[13] += w * v3.y; acc[14] += w * v3.z; acc[15] += w * v3.w;
    }
    float inv = 1.f / (den + 1e-16f);
    float r[16];
#pragma unroll
    for (int c = 0; c < 16; ++c) {
        float v = acc[c] * inv + b2[c];
        r[c] = (v > 0.f) ? v : 0.f;          // relu
    }
#pragma unroll
    for (int cp = 0; cp < 16; ++cp) {
        float s2 = 0.f;
#pragma unroll
        for (int c = 0; c < 16; ++c) s2 += r[c] * Wg[c * 16 + cp];
        xw[(size_t)dst * 16 + cp] = s2;
    }
    dinv[dst] = 1.f / sqrtf((float)(end - beg));   // deg >= 1 (self-loop)
}

// ---------------------------------------------------------------------------
// GCN edge pass: out = sum norm * xw[src] + bg
// ---------------------------------------------------------------------------
__global__ void gcn_kernel(const int* __restrict__ rowptr, const int* __restrict__ col,
                           const float* __restrict__ xw, const float* __restrict__ dinv,
                           const float* __restrict__ bg, float* __restrict__ out, int n) {
    int dst = blockIdx.x * blockDim.x + threadIdx.x;
    if (dst >= n) return;
    int beg = rowptr[dst], end = rowptr[dst + 1];
    float di = dinv[dst];
    float acc[16] = {};
    for (int j = beg; j < end; ++j) {
        int s = col[j];
        float nm = dinv[s] * di;
        const float4* xp = reinterpret_cast<const float4*>(xw + (size_t)s * 16);
        float4 v0 = xp[0], v1 = xp[1], v2 = xp[2], v3 = xp[3];
        acc[0]  += nm * v0.x; acc[1]  += nm * v0.y; acc[2]  += nm * v0.z; acc[3]  += nm * v0.w;
        acc[4]  += nm * v1.x; acc[5]  += nm * v1.y; acc[6]  += nm * v1.z; acc[7]  += nm * v1.w;
        acc[8]  += nm * v2.x; acc[9]  += nm * v2.y; acc[10] += nm * v2.z; acc[11] += nm * v2.w;
        acc[12] += nm * v3.x; acc[13] += nm * v3.y; acc[14] += nm * v3.z; acc[15] += nm * v3.w;
    }
#pragma unroll
    for (int c = 0; c < 16; ++c)
        out[(size_t)dst * 16 + c] = acc[c] + bg[c];
}

// ---------------------------------------------------------------------------
extern "C" void kernel_launch(void* const* d_in, const int* in_sizes, int n_in,
                              void* d_out, int out_size, void* d_ws, size_t ws_size,
                              hipStream_t stream) {
    const float* x    = (const float*)d_in[0];
    const int*   ei   = (const int*)d_in[1];     // [2,E] int
    const float* W1   = (const float*)d_in[2];
    const float* a1s  = (const float*)d_in[3];
    const float* a1d  = (const float*)d_in[4];
    const float* b1   = (const float*)d_in[5];
    const float* W2   = (const float*)d_in[6];
    const float* a2s  = (const float*)d_in[7];
    const float* a2d  = (const float*)d_in[8];
    const float* b2   = (const float*)d_in[9];
    const float* Wg   = (const float*)d_in[10];
    const float* bg   = (const float*)d_in[11];
    float* out = (float*)d_out;

    const int N = in_sizes[0] / F_IN;
    const int E = in_sizes[1] / 2;
    const int Etot = E + N;

    // ws carve-up (256B aligned regions)
    char* base = (char*)d_ws;
    size_t off = 0;
    auto alloc = [&](size_t bytes) -> char* {
        char* p = base + off;
        off = (off + bytes + 255) & ~(size_t)255;
        return p;
    };
    float* h    = (float*)alloc((size_t)N * 64 * 4);
    float* als  = (float*)alloc((size_t)N * 8 * 4);
    float* ald  = (float*)alloc((size_t)N * 8 * 4);
    float* out1 = (float*)alloc((size_t)N * 64 * 4);
    float* h2   = (float*)alloc((size_t)N * 16 * 4);
    float* al2s = (float*)alloc((size_t)N * 4);
    float* al2d = (float*)alloc((size_t)N * 4);
    float* xw   = (float*)alloc((size_t)N * 16 * 4);
    float* dinv = (float*)alloc((size_t)N * 4);
    int*   deg  = (int*)alloc((size_t)N * 4);
    int*   rowptr = (int*)alloc((size_t)(N + 1) * 4);
    int*   bsum = (int*)alloc(512 * 4);
    int*   bexcl= (int*)alloc(512 * 4);
    int*   col  = (int*)alloc((size_t)Etot * 4);
    int*   pos  = (int*)alloc((size_t)Etot * 4);
    float* Wt   = (float*)alloc((size_t)64 * KPAD * 4);   // transposed+padded W1

    const int* ei_src = ei;
    const int* ei_dst = ei + E;

    const int TB = 256;
    int nbN  = (N + TB - 1) / TB;               // 391
    int nbE4 = (Etot + TB * 4 - 1) / (TB * 4);  // 4 edges/thread
    int nbG  = (N + BM - 1) / BM;               // mfma gemm blocks (782)
    int nbA  = (N * 8 + TB - 1) / TB;           // gat1 threads

    // CSR build
    zero_int_kernel<<<nbN, TB, 0, stream>>>(deg, N);
    deg_pos_kernel<<<nbE4, TB, 0, stream>>>(ei_dst, deg, pos, E, N);
    scan1_kernel<<<nbN, TB, 0, stream>>>(deg, bsum, N);
    scan2_kernel<<<1, 512, 0, stream>>>(bsum, bexcl, nbN);
    scan3_kernel<<<nbN, TB, 0, stream>>>(deg, bexcl, rowptr, N);
    fill2_kernel<<<nbE4, TB, 0, stream>>>(ei_src, ei_dst, rowptr, pos, col, E, N);

    // Dense pipeline
    transposeW1_kernel<<<(64 * KPAD + TB - 1) / TB, TB, 0, stream>>>(W1, Wt);
    gemm1_mfma_kernel<<<nbG, TB, 0, stream>>>(x, Wt, h, N);
    proj_al1_kernel<<<nbN, TB, 0, stream>>>(h, a1s, a1d, als, ald, N);
    gat1_edge_kernel<<<nbA, TB, 0, stream>>>(rowptr, col, als, ald, h, b1, out1, N);
    proj2_kernel<<<nbN, TB, 0, stream>>>(out1, W2, a2s, a2d, h2, al2s, al2d, N);
    gat2_edge_kernel<<<nbN, TB, 0, stream>>>(rowptr, col, al2s, al2d, h2, b2, Wg, xw, dinv, N);
    gcn_kernel<<<nbN, TB, 0, stream>>>(rowptr, col, xw, dinv, bg, out, N);
}